// Round 5
// baseline (3797.617 us; speedup 1.0000x reference)
//
#include <hip/hip_runtime.h>
#include <cstdint>

// Problem constants (from reference)
#define TSEQ 224
#define HID 128
#define NSEQ 1280           // BATCHES*SUB = 64*20
#define KTOT (TSEQ*HID)     // 28672
#define NB 16               // sequences per LSTM block
#define INTER 64
#define SUB 20

typedef short bf16x8 __attribute__((ext_vector_type(8)));
typedef float f32x4  __attribute__((ext_vector_type(4)));

__device__ __forceinline__ float fast_sigmoid(float a) {
  float e = __expf(-a);
  return __builtin_amdgcn_rcpf(1.0f + e);
}
__device__ __forceinline__ float fast_tanh(float a) {
  float e = __expf(-2.0f * a);
  return fmaf(2.0f, __builtin_amdgcn_rcpf(1.0f + e), -1.0f);
}

// Truncate-split packing: two fp32 -> one uint holding 2 bf16 (hi parts),
// and residual lo parts. Truncation keeps residual exactly representable.
__device__ __forceinline__ void split2(float a, float b,
                                       unsigned int& hi, unsigned int& lo) {
  unsigned int ua = __float_as_uint(a), ub = __float_as_uint(b);
  unsigned int ha = ua & 0xFFFF0000u,  hb = ub & 0xFFFF0000u;
  float ra = a - __uint_as_float(ha);
  float rb = b - __uint_as_float(hb);
  hi = (ha >> 16) | hb;
  lo = (__float_as_uint(ra) >> 16) | (__float_as_uint(rb) & 0xFFFF0000u);
}

// ---------------------------------------------------------------------------
// Fused MFMA LSTM + GEMM1. 80 blocks x 512 threads; block owns NB=16 seqs.
// LSTM: gates[512x16] = W'[512x128] @ h[128x16], 16x16x32 bf16 MFMA, 3-pass
// split-bf16 (exact at harness granularity, R4: absmax 0.0). W' row-permuted
// so lane holds all 4 gates of one unit -> in-lane c/h update.
// FUSION: feats[64x16] += W1_t[64x128] @ h_t[128x16] reuses the SAME split-h
// B-fragments; W1 A-frags stream from L2 (W1 = 7.3 MB, resident). h is
// masked to 0 at t >= len[n] (recurrence past len is unobservable), so the
// fused accumulation matches the reference's zero-masked hs exactly and the
// 146 MB hs intermediate + separate gemm1 kernel are eliminated.
// Iteration t multiplies W1 slice (t-1) with resident h_{t-1} frags; an
// epilogue handles the final slice. feats partials (kt-halves in wave pairs)
// are reduced through LDS at the end.
// ---------------------------------------------------------------------------
__attribute__((amdgpu_waves_per_eu(2, 2)))
__global__ __launch_bounds__(512) void lstm_fused(
    const float* __restrict__ x,      // [NSEQ, TSEQ]
    const float* __restrict__ W_ih,   // [512, 1]
    const float* __restrict__ W_hh,   // [512, 128]
    const float* __restrict__ b_ih,   // [512]
    const float* __restrict__ b_hh,   // [512]
    const float* __restrict__ W1,     // [64, KTOT]
    float* __restrict__ feats)        // [NSEQ, 64]
{
  const int tid = threadIdx.x;
  const int w   = tid >> 6;          // wave 0..7
  const int l   = tid & 63;          // lane
  const int lm  = l & 15;            // seq col n (D/B); A-frag row
  const int lq  = l >> 4;            // quad
  const int n0  = blockIdx.x * NB;

  __shared__ float s_x[NB][228];                         // padded: bank spread
  __shared__ int   s_fz[NB];
  __shared__ int   s_len[NB];
  __shared__ int   s_maxlen;
  __shared__ __align__(16) unsigned short s_hhi[4][64][8];  // B-frags hi [kt][lane][j]
  __shared__ __align__(16) unsigned short s_hlo[4][64][8];  // B-frags lo
  __shared__ float s_hT[HID][17];                        // h fp32 [unit][seq]
  __shared__ __align__(16) float s_red[2][4][64][4];     // feats partials [kh][it][lane][reg]

  // ---- stage x (coalesced: 32 threads per sequence), find first zero
  if (tid < NB) s_fz[tid] = TSEQ;
  __syncthreads();
  {
    const int n = tid >> 5, j = tid & 31;
    const float* xrow = x + (size_t)(n0 + n) * TSEQ;
    #pragma unroll
    for (int i = 0; i < 7; ++i) {
      int t = j + 32 * i;
      float v = xrow[t];
      s_x[n][t] = v;
      if (v == 0.0f) atomicMin(&s_fz[n], t);
    }
  }
  // zero-init B-frag buffers (h0 = 0)
  {
    unsigned int* ph = (unsigned int*)&s_hhi[0][0][0];
    unsigned int* pl = (unsigned int*)&s_hlo[0][0][0];
    ph[tid] = 0; ph[tid + 512] = 0;
    pl[tid] = 0; pl[tid + 512] = 0;
  }
  __syncthreads();
  if (tid < NB) {
    int fz = s_fz[tid];
    s_len[tid] = (fz == 0 || fz >= TSEQ) ? TSEQ : fz + 1;  // reference quirk
  }
  __syncthreads();
  if (tid == 0) {
    int m = 0;
    for (int n = 0; n < NB; ++n) m = max(m, s_len[n]);
    s_maxlen = m;
  }
  __syncthreads();
  const int maxlen = s_maxlen;
  const int len_lm = s_len[lm];      // len of the seq this lane updates/owns

  // ---- load LSTM A-fragments (W' permuted, split hi/lo) + per-lane consts
  bf16x8 whi[4][4], wlo[4][4];       // [mt][kt]
  #pragma unroll
  for (int mt = 0; mt < 4; ++mt) {
    const int MT   = w * 4 + mt;
    const int orow = (lm & 3) * 128 + MT * 4 + (lm >> 2);  // W' row permutation
    const float* wr = W_hh + (size_t)orow * HID;
    #pragma unroll
    for (int kt = 0; kt < 4; ++kt) {
      const int k0 = kt * 32 + lq * 8;
      union { bf16x8 v; unsigned int u[4]; } hi, lo;
      #pragma unroll
      for (int p = 0; p < 4; ++p)
        split2(wr[k0 + 2 * p], wr[k0 + 2 * p + 1], hi.u[p], lo.u[p]);
      whi[mt][kt] = hi.v;
      wlo[mt][kt] = lo.v;
    }
  }
  float bias_[4][4], wih_[4][4], c_[4];
  #pragma unroll
  for (int mt = 0; mt < 4; ++mt) {
    const int u_ = (w * 4 + mt) * 4 + lq;
    c_[mt] = 0.0f;
    #pragma unroll
    for (int r = 0; r < 4; ++r) {
      const int g = r * 128 + u_;       // r: 0=i 1=f 2=g~ 3=o
      bias_[mt][r] = b_ih[g] + b_hh[g];
      wih_[mt][r]  = W_ih[g];
    }
  }
  // ---- GEMM1 per-wave constants: wave w owns i-tile it = w>>1, kt-half kh
  const int it = w >> 1;
  const int kh = w & 1;
  const float* w1base = W1 + (size_t)(it * 16 + lm) * KTOT + (2 * kh) * 32 + lq * 8;
  f32x4 facc = {0.f, 0.f, 0.f, 0.f};

  // repack role constants
  const int rp_kt = tid >> 6;                 // repack (tid<256)
  const int rp_l  = tid & 63;
  const int rp_n  = rp_l & 15, rp_q = rp_l >> 4;

  for (int t = 0; t < maxlen; ++t) {
    // B-fragments for this step = h_{t-1} (written by previous repack / init)
    bf16x8 bh[4], bl[4];
    #pragma unroll
    for (int kt = 0; kt < 4; ++kt) {
      bh[kt] = *(const bf16x8*)&s_hhi[kt][l][0];
      bl[kt] = *(const bf16x8*)&s_hlo[kt][l][0];
    }
    // W1 slice (t-1) A-fragments (skip t=0: h_{-1}=0 contributes nothing)
    bf16x8 w1hi[2], w1lo[2];
    if (t > 0) {
      #pragma unroll
      for (int kt2 = 0; kt2 < 2; ++kt2) {
        const float* pw = w1base + (size_t)(t - 1) * HID + kt2 * 32;
        union { bf16x8 v; unsigned int u[4]; } hi, lo;
        #pragma unroll
        for (int p = 0; p < 4; ++p)
          split2(pw[2 * p], pw[2 * p + 1], hi.u[p], lo.u[p]);
        w1hi[kt2] = hi.v;
        w1lo[kt2] = lo.v;
      }
    }
    const float xv = s_x[lm][t];
    f32x4 acc[4];
    #pragma unroll
    for (int mt = 0; mt < 4; ++mt)
      #pragma unroll
      for (int r = 0; r < 4; ++r)
        acc[mt][r] = fmaf(wih_[mt][r], xv, bias_[mt][r]);
    #pragma unroll
    for (int kt = 0; kt < 4; ++kt)
      #pragma unroll
      for (int mt = 0; mt < 4; ++mt)
        acc[mt] = __builtin_amdgcn_mfma_f32_16x16x32_bf16(whi[mt][kt], bh[kt], acc[mt], 0, 0, 0);
    #pragma unroll
    for (int kt = 0; kt < 4; ++kt)
      #pragma unroll
      for (int mt = 0; mt < 4; ++mt)
        acc[mt] = __builtin_amdgcn_mfma_f32_16x16x32_bf16(wlo[mt][kt], bh[kt], acc[mt], 0, 0, 0);
    #pragma unroll
    for (int kt = 0; kt < 4; ++kt)
      #pragma unroll
      for (int mt = 0; mt < 4; ++mt)
        acc[mt] = __builtin_amdgcn_mfma_f32_16x16x32_bf16(whi[mt][kt], bl[kt], acc[mt], 0, 0, 0);
    // fused GEMM1 for slice t-1 (3-pass), reusing the same B-fragments
    if (t > 0) {
      #pragma unroll
      for (int kt2 = 0; kt2 < 2; ++kt2) {
        const int kt = 2 * kh + kt2;
        facc = __builtin_amdgcn_mfma_f32_16x16x32_bf16(w1hi[kt2], bh[kt], facc, 0, 0, 0);
        facc = __builtin_amdgcn_mfma_f32_16x16x32_bf16(w1hi[kt2], bl[kt], facc, 0, 0, 0);
        facc = __builtin_amdgcn_mfma_f32_16x16x32_bf16(w1lo[kt2], bh[kt], facc, 0, 0, 0);
      }
    }
    // in-lane LSTM update: lane owns unit u = (w*4+mt)*4+lq, seq lm
    #pragma unroll
    for (int mt = 0; mt < 4; ++mt) {
      float i_ = fast_sigmoid(acc[mt][0]);
      float f_ = fast_sigmoid(acc[mt][1]);
      float g_ = fast_tanh(acc[mt][2]);
      float o_ = fast_sigmoid(acc[mt][3]);
      c_[mt] = fmaf(f_, c_[mt], i_ * g_);
      float h_ = o_ * fast_tanh(c_[mt]);
      h_ = (t < len_lm) ? h_ : 0.0f;      // mask: matches reference hs zeroing
      s_hT[(w * 4 + mt) * 4 + lq][lm] = h_;
    }
    __syncthreads();
    // repack h_t -> B-frag layout (tid<256); other waves idle here
    if (tid < 256) {
      union { bf16x8 v; unsigned int u[4]; } hi, lo;
      #pragma unroll
      for (int p = 0; p < 4; ++p) {
        float a = s_hT[rp_kt * 32 + rp_q * 8 + 2 * p][rp_n];
        float b = s_hT[rp_kt * 32 + rp_q * 8 + 2 * p + 1][rp_n];
        split2(a, b, hi.u[p], lo.u[p]);
      }
      *(bf16x8*)&s_hhi[rp_kt][rp_l][0] = hi.v;
      *(bf16x8*)&s_hlo[rp_kt][rp_l][0] = lo.v;
    }
    __syncthreads();
  }

  // ---- epilogue: GEMM1 for the final slice (maxlen-1) with h_{maxlen-1}
  {
    const int tf = maxlen - 1;
    bf16x8 w1hi[2], w1lo[2];
    #pragma unroll
    for (int kt2 = 0; kt2 < 2; ++kt2) {
      const float* pw = w1base + (size_t)tf * HID + kt2 * 32;
      union { bf16x8 v; unsigned int u[4]; } hi, lo;
      #pragma unroll
      for (int p = 0; p < 4; ++p)
        split2(pw[2 * p], pw[2 * p + 1], hi.u[p], lo.u[p]);
      w1hi[kt2] = hi.v;
      w1lo[kt2] = lo.v;
    }
    #pragma unroll
    for (int kt2 = 0; kt2 < 2; ++kt2) {
      const int kt = 2 * kh + kt2;
      bf16x8 bh = *(const bf16x8*)&s_hhi[kt][l][0];
      bf16x8 bl = *(const bf16x8*)&s_hlo[kt][l][0];
      facc = __builtin_amdgcn_mfma_f32_16x16x32_bf16(w1hi[kt2], bh, facc, 0, 0, 0);
      facc = __builtin_amdgcn_mfma_f32_16x16x32_bf16(w1hi[kt2], bl, facc, 0, 0, 0);
      facc = __builtin_amdgcn_mfma_f32_16x16x32_bf16(w1lo[kt2], bh, facc, 0, 0, 0);
    }
  }

  // ---- reduce kt-halves across wave pairs, write feats[n][i]
  *(f32x4*)&s_red[kh][it][l][0] = facc;
  __syncthreads();
  {
    const int n     = tid >> 5;          // 0..15
    const int ipair = tid & 31;          // 0..31
    const int i0    = ipair * 2;
    const int tile  = i0 >> 4;
    const int lqi   = (i0 & 15) >> 2;
    const int r0    = i0 & 3;            // 0 or 2
    const int lane  = lqi * 16 + n;
    float v0 = s_red[0][tile][lane][r0]     + s_red[1][tile][lane][r0];
    float v1 = s_red[0][tile][lane][r0 + 1] + s_red[1][tile][lane][r0 + 1];
    *(float2*)(feats + (size_t)(n0 + n) * INTER + i0) = make_float2(v0, v1);
  }
}

// ---------------------------------------------------------------------------
// GEMM2: out[b][m] = b2[m] + sum_{s,i} (feats[b*20+s][i]+b1[i]) * W2[m][s*64+i]
// 64 blocks x 64 threads; wave-reduce.
// ---------------------------------------------------------------------------
__global__ __launch_bounds__(64) void gemm2_kernel(
    const float* __restrict__ feats,  // [NSEQ, 64]
    const float* __restrict__ b1,     // [64]
    const float* __restrict__ W2,     // [2, 1280]
    const float* __restrict__ b2,     // [2]
    float* __restrict__ out)          // [64, 2]
{
  const int b = blockIdx.x;
  const int i = threadIdx.x;
  const float bi = b1[i];
  float acc0 = 0.f, acc1 = 0.f;
  #pragma unroll
  for (int s = 0; s < SUB; ++s) {
    float f = feats[(size_t)(b * SUB + s) * INTER + i] + bi;
    acc0 = fmaf(f, W2[s * INTER + i], acc0);
    acc1 = fmaf(f, W2[1280 + s * INTER + i], acc1);
  }
  #pragma unroll
  for (int off = 32; off > 0; off >>= 1) {
    acc0 += __shfl_down(acc0, off);
    acc1 += __shfl_down(acc1, off);
  }
  if (i == 0) {
    out[b * 2 + 0] = acc0 + b2[0];
    out[b * 2 + 1] = acc1 + b2[1];
  }
}

// ---------------------------------------------------------------------------
extern "C" void kernel_launch(void* const* d_in, const int* in_sizes, int n_in,
                              void* d_out, int out_size, void* d_ws, size_t ws_size,
                              hipStream_t stream) {
  const float* x    = (const float*)d_in[0];
  // d_in[1] = metadata: unused by the reference
  const float* W_ih = (const float*)d_in[2];
  const float* W_hh = (const float*)d_in[3];
  const float* b_ih = (const float*)d_in[4];
  const float* b_hh = (const float*)d_in[5];
  const float* W1   = (const float*)d_in[6];
  const float* b1   = (const float*)d_in[7];
  const float* W2   = (const float*)d_in[8];
  const float* b2   = (const float*)d_in[9];
  float* out = (float*)d_out;

  // workspace: feats [1280*64] f32 (327 KB)
  float* feats = (float*)d_ws;

  lstm_fused<<<NSEQ / NB, 512, 0, stream>>>(x, W_ih, W_hh, b_ih, b_hh, W1, feats);
  gemm2_kernel<<<64, 64, 0, stream>>>(feats, b1, W2, b2, out);
}

// Round 6
// 488.421 us; speedup vs baseline: 7.7753x; 7.7753x over previous
//
#include <hip/hip_runtime.h>
#include <cstdint>

// Problem constants (from reference)
#define TSEQ 224
#define HID 128
#define NSEQ 1280           // BATCHES*SUB = 64*20
#define KTOT (TSEQ*HID)     // 28672
#define NB 16               // sequences per LSTM block
#define INTER 64
#define SUB 20

typedef short bf16x8 __attribute__((ext_vector_type(8)));
typedef float f32x4  __attribute__((ext_vector_type(4)));

__device__ __forceinline__ float fast_sigmoid(float a) {
  float e = __expf(-a);
  return __builtin_amdgcn_rcpf(1.0f + e);
}
__device__ __forceinline__ float fast_tanh(float a) {
  float e = __expf(-2.0f * a);
  return fmaf(2.0f, __builtin_amdgcn_rcpf(1.0f + e), -1.0f);
}

// Truncate-split packing: two fp32 -> one uint holding 2 bf16 (hi parts),
// and residual lo parts. Truncation keeps residual exactly representable.
__device__ __forceinline__ void split2(float a, float b,
                                       unsigned int& hi, unsigned int& lo) {
  unsigned int ua = __float_as_uint(a), ub = __float_as_uint(b);
  unsigned int ha = ua & 0xFFFF0000u,  hb = ub & 0xFFFF0000u;
  float ra = a - __uint_as_float(ha);
  float rb = b - __uint_as_float(hb);
  hi = (ha >> 16) | hb;
  lo = (__float_as_uint(ra) >> 16) | (__float_as_uint(rb) & 0xFFFF0000u);
}

// ---------------------------------------------------------------------------
// prep_w1: repack W1 [64, KTOT] fp32 into split-bf16 per-lane fragment layout.
// chunk = t*16 + it*4 + kh*2 + kt2 ; within chunk: [lane(64)][hi8|lo8] ushort.
// Consumer lane l of wave (it,kh) then loads 32 contiguous bytes — fully
// coalesced, no per-step split2 VALU, no scattered 114KB-stride reads (which
// in R5 aliased to a single L1 set AND blew the register budget -> scratch
// spill of the resident LSTM weights = the 10x regression).
// ---------------------------------------------------------------------------
__global__ __launch_bounds__(256) void prep_w1(
    const float* __restrict__ W1, unsigned short* __restrict__ W1p)
{
  const int idx   = blockIdx.x * 256 + threadIdx.x;  // 229376 total
  const int lane  = idx & 63;
  const int chunk = idx >> 6;           // t*16 + it*4 + kh*2 + kt2
  const int kt2   = chunk & 1;
  const int kh    = (chunk >> 1) & 1;
  const int it    = (chunk >> 2) & 3;
  const int t     = chunk >> 4;
  const int row   = it * 16 + (lane & 15);
  const int col   = t * 128 + kh * 64 + kt2 * 32 + (lane >> 4) * 8;
  const float* src = W1 + (size_t)row * KTOT + col;
  union { bf16x8 v; unsigned int u[4]; } hi, lo;
  #pragma unroll
  for (int p = 0; p < 4; ++p) split2(src[2 * p], src[2 * p + 1], hi.u[p], lo.u[p]);
  unsigned short* dst = W1p + (size_t)chunk * 1024 + lane * 16;
  *(bf16x8*)dst       = hi.v;
  *(bf16x8*)(dst + 8) = lo.v;
}

// ---------------------------------------------------------------------------
// Fused MFMA LSTM + GEMM1. 80 blocks x 512 threads; block owns NB=16 seqs.
// LSTM: gates[512x16] = W'[512x128] @ h[128x16], 16x16x32 bf16 MFMA, 3-pass
// split-bf16. W' row-permuted so lane holds all 4 gates of one unit ->
// in-lane c/h update. GEMM1 fused: feats += W1_t @ h_t reusing the same split
// h B-fragments; W1 frags now pre-packed (prep_w1) -> 2 coalesced 32B loads.
// h masked to 0 at t >= len[n]; hs intermediate eliminated entirely.
// kt-outer MFMA loop keeps bh/bl live ranges short (register relief).
// ---------------------------------------------------------------------------
__attribute__((amdgpu_waves_per_eu(2, 2)))
__global__ __launch_bounds__(512) void lstm_fused(
    const float* __restrict__ x,      // [NSEQ, TSEQ]
    const float* __restrict__ W_ih,   // [512, 1]
    const float* __restrict__ W_hh,   // [512, 128]
    const float* __restrict__ b_ih,   // [512]
    const float* __restrict__ b_hh,   // [512]
    const unsigned short* __restrict__ W1p,  // packed split-bf16 W1
    float* __restrict__ feats)        // [NSEQ, 64]
{
  const int tid = threadIdx.x;
  const int w   = tid >> 6;          // wave 0..7
  const int l   = tid & 63;          // lane
  const int lm  = l & 15;            // seq col n (D/B); A-frag row
  const int lq  = l >> 4;            // quad
  const int n0  = blockIdx.x * NB;

  __shared__ float s_x[NB][228];                         // padded: bank spread
  __shared__ int   s_fz[NB];
  __shared__ int   s_len[NB];
  __shared__ int   s_maxlen;
  __shared__ __align__(16) unsigned short s_hhi[4][64][8];  // B-frags hi [kt][lane][j]
  __shared__ __align__(16) unsigned short s_hlo[4][64][8];  // B-frags lo
  __shared__ float s_hT[HID][17];                        // h fp32 [unit][seq]
  __shared__ __align__(16) float s_red[2][4][64][4];     // feats partials [kh][it][lane][reg]

  // ---- stage x (coalesced: 32 threads per sequence), find first zero
  if (tid < NB) s_fz[tid] = TSEQ;
  __syncthreads();
  {
    const int n = tid >> 5, j = tid & 31;
    const float* xrow = x + (size_t)(n0 + n) * TSEQ;
    #pragma unroll
    for (int i = 0; i < 7; ++i) {
      int t = j + 32 * i;
      float v = xrow[t];
      s_x[n][t] = v;
      if (v == 0.0f) atomicMin(&s_fz[n], t);
    }
  }
  // zero-init B-frag buffers (h0 = 0)
  {
    unsigned int* ph = (unsigned int*)&s_hhi[0][0][0];
    unsigned int* pl = (unsigned int*)&s_hlo[0][0][0];
    ph[tid] = 0; ph[tid + 512] = 0;
    pl[tid] = 0; pl[tid + 512] = 0;
  }
  __syncthreads();
  if (tid < NB) {
    int fz = s_fz[tid];
    s_len[tid] = (fz == 0 || fz >= TSEQ) ? TSEQ : fz + 1;  // reference quirk
  }
  __syncthreads();
  if (tid == 0) {
    int m = 0;
    for (int n = 0; n < NB; ++n) m = max(m, s_len[n]);
    s_maxlen = m;
  }
  __syncthreads();
  const int maxlen = s_maxlen;
  const int len_lm = s_len[lm];      // len of the seq this lane updates/owns

  // ---- load LSTM A-fragments (W' permuted, split hi/lo) + per-lane consts
  bf16x8 whi[4][4], wlo[4][4];       // [mt][kt]
  #pragma unroll
  for (int mt = 0; mt < 4; ++mt) {
    const int MT   = w * 4 + mt;
    const int orow = (lm & 3) * 128 + MT * 4 + (lm >> 2);  // W' row permutation
    const float* wr = W_hh + (size_t)orow * HID;
    #pragma unroll
    for (int kt = 0; kt < 4; ++kt) {
      const int k0 = kt * 32 + lq * 8;
      union { bf16x8 v; unsigned int u[4]; } hi, lo;
      #pragma unroll
      for (int p = 0; p < 4; ++p)
        split2(wr[k0 + 2 * p], wr[k0 + 2 * p + 1], hi.u[p], lo.u[p]);
      whi[mt][kt] = hi.v;
      wlo[mt][kt] = lo.v;
    }
  }
  float bias_[4][4], wih_[4][4], c_[4];
  #pragma unroll
  for (int mt = 0; mt < 4; ++mt) {
    const int u_ = (w * 4 + mt) * 4 + lq;
    c_[mt] = 0.0f;
    #pragma unroll
    for (int r = 0; r < 4; ++r) {
      const int g = r * 128 + u_;       // r: 0=i 1=f 2=g~ 3=o
      bias_[mt][r] = b_ih[g] + b_hh[g];
      wih_[mt][r]  = W_ih[g];
    }
  }
  // ---- GEMM1 per-wave constants: wave w owns i-tile it = w>>1, kt-half kh
  const int it = w >> 1;
  const int kh = w & 1;
  const unsigned short* w1p_base = W1p + ((size_t)it * 4 + kh * 2) * 1024 + l * 16;
  f32x4 facc = {0.f, 0.f, 0.f, 0.f};

  // repack role constants
  const int rp_kt = tid >> 6;                 // repack (tid<256)
  const int rp_l  = tid & 63;
  const int rp_n  = rp_l & 15, rp_q = rp_l >> 4;

  for (int t = 0; t < maxlen; ++t) {
    // W1 slice (t-1) fragments: 2 coalesced 32B loads (skip t=0: h_{-1}=0)
    bf16x8 w1hi[2], w1lo[2];
    if (t > 0) {
      const unsigned short* p0 = w1p_base + (size_t)(t - 1) * 16384;
      w1hi[0] = *(const bf16x8*)p0;
      w1lo[0] = *(const bf16x8*)(p0 + 8);
      w1hi[1] = *(const bf16x8*)(p0 + 1024);
      w1lo[1] = *(const bf16x8*)(p0 + 1024 + 8);
    }
    const float xv = s_x[lm][t];
    f32x4 acc[4];
    #pragma unroll
    for (int mt = 0; mt < 4; ++mt)
      #pragma unroll
      for (int r = 0; r < 4; ++r)
        acc[mt][r] = fmaf(wih_[mt][r], xv, bias_[mt][r]);
    // kt-outer: bh/bl live ranges short; GEMM1 folded in (wave-uniform guard)
    #pragma unroll
    for (int kt = 0; kt < 4; ++kt) {
      bf16x8 bh = *(const bf16x8*)&s_hhi[kt][l][0];
      bf16x8 bl = *(const bf16x8*)&s_hlo[kt][l][0];
      #pragma unroll
      for (int mt = 0; mt < 4; ++mt) {
        acc[mt] = __builtin_amdgcn_mfma_f32_16x16x32_bf16(whi[mt][kt], bh, acc[mt], 0, 0, 0);
        acc[mt] = __builtin_amdgcn_mfma_f32_16x16x32_bf16(wlo[mt][kt], bh, acc[mt], 0, 0, 0);
        acc[mt] = __builtin_amdgcn_mfma_f32_16x16x32_bf16(whi[mt][kt], bl, acc[mt], 0, 0, 0);
      }
      if (t > 0 && (kt >> 1) == kh) {
        const int kt2 = kt & 1;
        facc = __builtin_amdgcn_mfma_f32_16x16x32_bf16(w1hi[kt2], bh, facc, 0, 0, 0);
        facc = __builtin_amdgcn_mfma_f32_16x16x32_bf16(w1hi[kt2], bl, facc, 0, 0, 0);
        facc = __builtin_amdgcn_mfma_f32_16x16x32_bf16(w1lo[kt2], bh, facc, 0, 0, 0);
      }
    }
    // in-lane LSTM update: lane owns unit u = (w*4+mt)*4+lq, seq lm
    #pragma unroll
    for (int mt = 0; mt < 4; ++mt) {
      float i_ = fast_sigmoid(acc[mt][0]);
      float f_ = fast_sigmoid(acc[mt][1]);
      float g_ = fast_tanh(acc[mt][2]);
      float o_ = fast_sigmoid(acc[mt][3]);
      c_[mt] = fmaf(f_, c_[mt], i_ * g_);
      float h_ = o_ * fast_tanh(c_[mt]);
      h_ = (t < len_lm) ? h_ : 0.0f;      // mask: matches reference hs zeroing
      s_hT[(w * 4 + mt) * 4 + lq][lm] = h_;
    }
    __syncthreads();
    // repack h_t -> B-frag layout (tid<256)
    if (tid < 256) {
      union { bf16x8 v; unsigned int u[4]; } hi, lo;
      #pragma unroll
      for (int p = 0; p < 4; ++p) {
        float a = s_hT[rp_kt * 32 + rp_q * 8 + 2 * p][rp_n];
        float b = s_hT[rp_kt * 32 + rp_q * 8 + 2 * p + 1][rp_n];
        split2(a, b, hi.u[p], lo.u[p]);
      }
      *(bf16x8*)&s_hhi[rp_kt][rp_l][0] = hi.v;
      *(bf16x8*)&s_hlo[rp_kt][rp_l][0] = lo.v;
    }
    __syncthreads();
  }

  // ---- epilogue: GEMM1 for the final slice (maxlen-1) with h_{maxlen-1}
  {
    const unsigned short* p0 = w1p_base + (size_t)(maxlen - 1) * 16384;
    bf16x8 w1hi[2], w1lo[2];
    w1hi[0] = *(const bf16x8*)p0;
    w1lo[0] = *(const bf16x8*)(p0 + 8);
    w1hi[1] = *(const bf16x8*)(p0 + 1024);
    w1lo[1] = *(const bf16x8*)(p0 + 1024 + 8);
    #pragma unroll
    for (int kt2 = 0; kt2 < 2; ++kt2) {
      const int kt = 2 * kh + kt2;
      bf16x8 bh = *(const bf16x8*)&s_hhi[kt][l][0];
      bf16x8 bl = *(const bf16x8*)&s_hlo[kt][l][0];
      facc = __builtin_amdgcn_mfma_f32_16x16x32_bf16(w1hi[kt2], bh, facc, 0, 0, 0);
      facc = __builtin_amdgcn_mfma_f32_16x16x32_bf16(w1hi[kt2], bl, facc, 0, 0, 0);
      facc = __builtin_amdgcn_mfma_f32_16x16x32_bf16(w1lo[kt2], bh, facc, 0, 0, 0);
    }
  }

  // ---- reduce kt-halves across wave pairs, write feats[n][i]
  *(f32x4*)&s_red[kh][it][l][0] = facc;
  __syncthreads();
  {
    const int n     = tid >> 5;          // 0..15
    const int ipair = tid & 31;          // 0..31
    const int i0    = ipair * 2;
    const int tile  = i0 >> 4;
    const int lqi   = (i0 & 15) >> 2;
    const int r0    = i0 & 3;            // 0 or 2
    const int lane  = lqi * 16 + n;
    float v0 = s_red[0][tile][lane][r0]     + s_red[1][tile][lane][r0];
    float v1 = s_red[0][tile][lane][r0 + 1] + s_red[1][tile][lane][r0 + 1];
    *(float2*)(feats + (size_t)(n0 + n) * INTER + i0) = make_float2(v0, v1);
  }
}

// ---------------------------------------------------------------------------
// GEMM2: out[b][m] = b2[m] + sum_{s,i} (feats[b*20+s][i]+b1[i]) * W2[m][s*64+i]
// ---------------------------------------------------------------------------
__global__ __launch_bounds__(64) void gemm2_kernel(
    const float* __restrict__ feats,  // [NSEQ, 64]
    const float* __restrict__ b1,     // [64]
    const float* __restrict__ W2,     // [2, 1280]
    const float* __restrict__ b2,     // [2]
    float* __restrict__ out)          // [64, 2]
{
  const int b = blockIdx.x;
  const int i = threadIdx.x;
  const float bi = b1[i];
  float acc0 = 0.f, acc1 = 0.f;
  #pragma unroll
  for (int s = 0; s < SUB; ++s) {
    float f = feats[(size_t)(b * SUB + s) * INTER + i] + bi;
    acc0 = fmaf(f, W2[s * INTER + i], acc0);
    acc1 = fmaf(f, W2[1280 + s * INTER + i], acc1);
  }
  #pragma unroll
  for (int off = 32; off > 0; off >>= 1) {
    acc0 += __shfl_down(acc0, off);
    acc1 += __shfl_down(acc1, off);
  }
  if (i == 0) {
    out[b * 2 + 0] = acc0 + b2[0];
    out[b * 2 + 1] = acc1 + b2[1];
  }
}

// ---------------------------------------------------------------------------
extern "C" void kernel_launch(void* const* d_in, const int* in_sizes, int n_in,
                              void* d_out, int out_size, void* d_ws, size_t ws_size,
                              hipStream_t stream) {
  const float* x    = (const float*)d_in[0];
  // d_in[1] = metadata: unused by the reference
  const float* W_ih = (const float*)d_in[2];
  const float* W_hh = (const float*)d_in[3];
  const float* b_ih = (const float*)d_in[4];
  const float* b_hh = (const float*)d_in[5];
  const float* W1   = (const float*)d_in[6];
  const float* b1   = (const float*)d_in[7];
  const float* W2   = (const float*)d_in[8];
  const float* b2   = (const float*)d_in[9];
  float* out = (float*)d_out;

  // workspace: W1p packed split-bf16 [229376*16 ushort = 7.34 MB] + feats [327 KB]
  unsigned short* W1p = (unsigned short*)d_ws;
  float* feats = (float*)((char*)d_ws + (size_t)229376 * 16 * sizeof(unsigned short));

  prep_w1<<<896, 256, 0, stream>>>(W1, W1p);
  lstm_fused<<<NSEQ / NB, 512, 0, stream>>>(x, W_ih, W_hh, b_ih, b_hh, W1p, feats);
  gemm2_kernel<<<64, 64, 0, stream>>>(feats, b1, W2, b2, out);
}

// Round 7
// 465.058 us; speedup vs baseline: 8.1659x; 1.0502x over previous
//
#include <hip/hip_runtime.h>
#include <cstdint>

// Problem constants (from reference)
#define TSEQ 224
#define HID 128
#define NSEQ 1280           // BATCHES*SUB = 64*20
#define KTOT (TSEQ*HID)     // 28672
#define NB 16               // sequences per LSTM block
#define INTER 64
#define SUB 20

typedef short bf16x8 __attribute__((ext_vector_type(8)));
typedef float f32x4  __attribute__((ext_vector_type(4)));

__device__ __forceinline__ float fast_sigmoid(float a) {
  float e = __expf(-a);
  return __builtin_amdgcn_rcpf(1.0f + e);
}
__device__ __forceinline__ float fast_tanh(float a) {
  float e = __expf(-2.0f * a);
  return fmaf(2.0f, __builtin_amdgcn_rcpf(1.0f + e), -1.0f);
}

// Truncate-split packing: two fp32 -> one uint holding 2 bf16 (hi parts),
// and residual lo parts. Truncation keeps residual exactly representable.
__device__ __forceinline__ void split2(float a, float b,
                                       unsigned int& hi, unsigned int& lo) {
  unsigned int ua = __float_as_uint(a), ub = __float_as_uint(b);
  unsigned int ha = ua & 0xFFFF0000u,  hb = ub & 0xFFFF0000u;
  float ra = a - __uint_as_float(ha);
  float rb = b - __uint_as_float(hb);
  hi = (ha >> 16) | hb;
  lo = (__float_as_uint(ra) >> 16) | (__float_as_uint(rb) & 0xFFFF0000u);
}

// ---------------------------------------------------------------------------
// prep_w1: repack W1 [64, KTOT] fp32 into split-bf16 per-lane fragment layout.
// chunk = t*16 + it*4 + kh*2 + kt2 ; within chunk: [lane(64)][hi8|lo8] ushort.
// ---------------------------------------------------------------------------
__global__ __launch_bounds__(256) void prep_w1(
    const float* __restrict__ W1, unsigned short* __restrict__ W1p)
{
  const int idx   = blockIdx.x * 256 + threadIdx.x;  // 229376 total
  const int lane  = idx & 63;
  const int chunk = idx >> 6;           // t*16 + it*4 + kh*2 + kt2
  const int kt2   = chunk & 1;
  const int kh    = (chunk >> 1) & 1;
  const int it    = (chunk >> 2) & 3;
  const int t     = chunk >> 4;
  const int row   = it * 16 + (lane & 15);
  const int col   = t * 128 + kh * 64 + kt2 * 32 + (lane >> 4) * 8;
  const float* src = W1 + (size_t)row * KTOT + col;
  union { bf16x8 v; unsigned int u[4]; } hi, lo;
  #pragma unroll
  for (int p = 0; p < 4; ++p) split2(src[2 * p], src[2 * p + 1], hi.u[p], lo.u[p]);
  unsigned short* dst = W1p + (size_t)chunk * 1024 + lane * 16;
  *(bf16x8*)dst       = hi.v;
  *(bf16x8*)(dst + 8) = lo.v;
}

// ---------------------------------------------------------------------------
// Fused MFMA LSTM + GEMM1, ONE barrier per step (R6 had two + an LDS
// round-trip: s_hT write -> barrier -> repack -> barrier; at 1 block/CU the
// whole CU stalled on that chain -> 4530 cyc/step at ~12% pipe busy).
// Now: update lanes write B-fragments DIRECTLY (packed hi16|lo16 uint32,
// 4x ds_write_b32, 2-way bank = free) into a DOUBLE-BUFFERED frag array;
// readers unpack with v_perm_b32 (2/dword). Layout per kt is two 16B-stride
// regions so ds_read_b128 stays conflict-free.
// ---------------------------------------------------------------------------
__attribute__((amdgpu_waves_per_eu(2, 2)))
__global__ __launch_bounds__(512) void lstm_fused(
    const float* __restrict__ x,      // [NSEQ, TSEQ]
    const float* __restrict__ W_ih,   // [512, 1]
    const float* __restrict__ W_hh,   // [512, 128]
    const float* __restrict__ b_ih,   // [512]
    const float* __restrict__ b_hh,   // [512]
    const unsigned short* __restrict__ W1p,  // packed split-bf16 W1
    float* __restrict__ feats)        // [NSEQ, 64]
{
  const int tid = threadIdx.x;
  const int w   = tid >> 6;          // wave 0..7
  const int l   = tid & 63;          // lane
  const int lm  = l & 15;            // seq col n (D/B); A-frag row
  const int lq  = l >> 4;            // quad
  const int n0  = blockIdx.x * NB;

  __shared__ float s_x[NB][228];                         // padded: bank spread
  __shared__ int   s_fz[NB];
  __shared__ int   s_len[NB];
  __shared__ int   s_maxlen;
  // h fragments, double-buffered, packed (hi16|lo16) per unit:
  // [buf][kt][region j>>2][lane][j&3]; unit = kt*32 + (lane>>4)*8 + j
  __shared__ __align__(16) unsigned int s_hfrag[2][4][2][64][4];   // 16 KB
  __shared__ __align__(16) float s_red[2][4][64][4];     // feats partials [kh][it][lane][reg]

  // ---- stage x (coalesced: 32 threads per sequence), find first zero
  if (tid < NB) s_fz[tid] = TSEQ;
  __syncthreads();
  {
    const int n = tid >> 5, j = tid & 31;
    const float* xrow = x + (size_t)(n0 + n) * TSEQ;
    #pragma unroll
    for (int i = 0; i < 7; ++i) {
      int t = j + 32 * i;
      float v = xrow[t];
      s_x[n][t] = v;
      if (v == 0.0f) atomicMin(&s_fz[n], t);
    }
  }
  // zero-init frag buffer 0 (h0 = 0): 2048 uints
  ((uint4*)&s_hfrag[0][0][0][0][0])[tid] = make_uint4(0u, 0u, 0u, 0u);
  __syncthreads();
  if (tid < NB) {
    int fz = s_fz[tid];
    s_len[tid] = (fz == 0 || fz >= TSEQ) ? TSEQ : fz + 1;  // reference quirk
  }
  __syncthreads();
  if (tid == 0) {
    int m = 0;
    for (int n = 0; n < NB; ++n) m = max(m, s_len[n]);
    s_maxlen = m;
  }
  __syncthreads();
  const int maxlen = s_maxlen;
  const int len_lm = s_len[lm];      // len of the seq this lane updates/owns

  // ---- load LSTM A-fragments (W' permuted, split hi/lo) + per-lane consts
  bf16x8 whi[4][4], wlo[4][4];       // [mt][kt]
  #pragma unroll
  for (int mt = 0; mt < 4; ++mt) {
    const int MT   = w * 4 + mt;
    const int orow = (lm & 3) * 128 + MT * 4 + (lm >> 2);  // W' row permutation
    const float* wr = W_hh + (size_t)orow * HID;
    #pragma unroll
    for (int kt = 0; kt < 4; ++kt) {
      const int k0 = kt * 32 + lq * 8;
      union { bf16x8 v; unsigned int u[4]; } hi, lo;
      #pragma unroll
      for (int p = 0; p < 4; ++p)
        split2(wr[k0 + 2 * p], wr[k0 + 2 * p + 1], hi.u[p], lo.u[p]);
      whi[mt][kt] = hi.v;
      wlo[mt][kt] = lo.v;
    }
  }
  float bias_[4][4], wih_[4][4], c_[4];
  #pragma unroll
  for (int mt = 0; mt < 4; ++mt) {
    const int u_ = (w * 4 + mt) * 4 + lq;
    c_[mt] = 0.0f;
    #pragma unroll
    for (int r = 0; r < 4; ++r) {
      const int g = r * 128 + u_;       // r: 0=i 1=f 2=g~ 3=o
      bias_[mt][r] = b_ih[g] + b_hh[g];
      wih_[mt][r]  = W_ih[g];
    }
  }
  // ---- GEMM1 per-wave constants: wave w owns i-tile it = w>>1, kt-half kh
  const int it = w >> 1;
  const int kh = w & 1;
  const unsigned short* w1p_base = W1p + ((size_t)it * 4 + kh * 2) * 1024 + l * 16;
  f32x4 facc = {0.f, 0.f, 0.f, 0.f};

  for (int t = 0; t < maxlen; ++t) {
    const int p = t & 1;
    // W1 slice (t-1) fragments: 2 coalesced 32B loads (skip t=0: h_{-1}=0)
    bf16x8 w1hi[2], w1lo[2];
    if (t > 0) {
      const unsigned short* p0 = w1p_base + (size_t)(t - 1) * 16384;
      w1hi[0] = *(const bf16x8*)p0;
      w1lo[0] = *(const bf16x8*)(p0 + 8);
      w1hi[1] = *(const bf16x8*)(p0 + 1024);
      w1lo[1] = *(const bf16x8*)(p0 + 1024 + 8);
    }
    const float xv = s_x[lm][t];
    f32x4 acc[4];
    #pragma unroll
    for (int mt = 0; mt < 4; ++mt)
      #pragma unroll
      for (int r = 0; r < 4; ++r)
        acc[mt][r] = fmaf(wih_[mt][r], xv, bias_[mt][r]);
    // kt-outer: read packed frags, unpack hi/lo via v_perm, MFMA
    #pragma unroll
    for (int kt = 0; kt < 4; ++kt) {
      uint4 ua = *(const uint4*)&s_hfrag[p][kt][0][l][0];
      uint4 ub = *(const uint4*)&s_hfrag[p][kt][1][l][0];
      union { bf16x8 v; unsigned int d[4]; } bh, bl;
      bh.d[0] = __builtin_amdgcn_perm(ua.y, ua.x, 0x07060302u);
      bl.d[0] = __builtin_amdgcn_perm(ua.y, ua.x, 0x05040100u);
      bh.d[1] = __builtin_amdgcn_perm(ua.w, ua.z, 0x07060302u);
      bl.d[1] = __builtin_amdgcn_perm(ua.w, ua.z, 0x05040100u);
      bh.d[2] = __builtin_amdgcn_perm(ub.y, ub.x, 0x07060302u);
      bl.d[2] = __builtin_amdgcn_perm(ub.y, ub.x, 0x05040100u);
      bh.d[3] = __builtin_amdgcn_perm(ub.w, ub.z, 0x07060302u);
      bl.d[3] = __builtin_amdgcn_perm(ub.w, ub.z, 0x05040100u);
      #pragma unroll
      for (int mt = 0; mt < 4; ++mt) {
        acc[mt] = __builtin_amdgcn_mfma_f32_16x16x32_bf16(whi[mt][kt], bh.v, acc[mt], 0, 0, 0);
        acc[mt] = __builtin_amdgcn_mfma_f32_16x16x32_bf16(wlo[mt][kt], bh.v, acc[mt], 0, 0, 0);
        acc[mt] = __builtin_amdgcn_mfma_f32_16x16x32_bf16(whi[mt][kt], bl.v, acc[mt], 0, 0, 0);
      }
      if (t > 0 && (kt >> 1) == kh) {
        const int kt2 = kt & 1;
        facc = __builtin_amdgcn_mfma_f32_16x16x32_bf16(w1hi[kt2], bh.v, facc, 0, 0, 0);
        facc = __builtin_amdgcn_mfma_f32_16x16x32_bf16(w1hi[kt2], bl.v, facc, 0, 0, 0);
        facc = __builtin_amdgcn_mfma_f32_16x16x32_bf16(w1lo[kt2], bh.v, facc, 0, 0, 0);
      }
    }
    // in-lane LSTM update + DIRECT packed frag write to buffer p^1
    #pragma unroll
    for (int mt = 0; mt < 4; ++mt) {
      float i_ = fast_sigmoid(acc[mt][0]);
      float f_ = fast_sigmoid(acc[mt][1]);
      float g_ = fast_tanh(acc[mt][2]);
      float o_ = fast_sigmoid(acc[mt][3]);
      c_[mt] = fmaf(f_, c_[mt], i_ * g_);
      float h_ = o_ * fast_tanh(c_[mt]);
      h_ = (t < len_lm) ? h_ : 0.0f;      // mask: matches reference hs zeroing
      unsigned int hb = __float_as_uint(h_);
      unsigned int hi = hb & 0xFFFF0000u;
      float lof = h_ - __uint_as_float(hi);
      unsigned int pk = hi | (__float_as_uint(lof) >> 16);
      const int u_ = 16 * w + 4 * mt + lq;  // unit this lane owns
      s_hfrag[p ^ 1][u_ >> 5][(u_ >> 2) & 1][((u_ >> 3) & 3) * 16 + lm][u_ & 3] = pk;
    }
    __syncthreads();
  }

  // ---- epilogue: GEMM1 for the final slice (maxlen-1) with h_{maxlen-1}
  {
    const int pe = maxlen & 1;
    const unsigned short* p0 = w1p_base + (size_t)(maxlen - 1) * 16384;
    bf16x8 w1hi[2], w1lo[2];
    w1hi[0] = *(const bf16x8*)p0;
    w1lo[0] = *(const bf16x8*)(p0 + 8);
    w1hi[1] = *(const bf16x8*)(p0 + 1024);
    w1lo[1] = *(const bf16x8*)(p0 + 1024 + 8);
    #pragma unroll
    for (int kt2 = 0; kt2 < 2; ++kt2) {
      const int kt = 2 * kh + kt2;
      uint4 ua = *(const uint4*)&s_hfrag[pe][kt][0][l][0];
      uint4 ub = *(const uint4*)&s_hfrag[pe][kt][1][l][0];
      union { bf16x8 v; unsigned int d[4]; } bh, bl;
      bh.d[0] = __builtin_amdgcn_perm(ua.y, ua.x, 0x07060302u);
      bl.d[0] = __builtin_amdgcn_perm(ua.y, ua.x, 0x05040100u);
      bh.d[1] = __builtin_amdgcn_perm(ua.w, ua.z, 0x07060302u);
      bl.d[1] = __builtin_amdgcn_perm(ua.w, ua.z, 0x05040100u);
      bh.d[2] = __builtin_amdgcn_perm(ub.y, ub.x, 0x07060302u);
      bl.d[2] = __builtin_amdgcn_perm(ub.y, ub.x, 0x05040100u);
      bh.d[3] = __builtin_amdgcn_perm(ub.w, ub.z, 0x07060302u);
      bl.d[3] = __builtin_amdgcn_perm(ub.w, ub.z, 0x05040100u);
      facc = __builtin_amdgcn_mfma_f32_16x16x32_bf16(w1hi[kt2], bh.v, facc, 0, 0, 0);
      facc = __builtin_amdgcn_mfma_f32_16x16x32_bf16(w1hi[kt2], bl.v, facc, 0, 0, 0);
      facc = __builtin_amdgcn_mfma_f32_16x16x32_bf16(w1lo[kt2], bh.v, facc, 0, 0, 0);
    }
  }

  // ---- reduce kt-halves across wave pairs, write feats[n][i]
  *(f32x4*)&s_red[kh][it][l][0] = facc;
  __syncthreads();
  {
    const int n     = tid >> 5;          // 0..15
    const int ipair = tid & 31;          // 0..31
    const int i0    = ipair * 2;
    const int tile  = i0 >> 4;
    const int lqi   = (i0 & 15) >> 2;
    const int r0    = i0 & 3;            // 0 or 2
    const int lane  = lqi * 16 + n;
    float v0 = s_red[0][tile][lane][r0]     + s_red[1][tile][lane][r0];
    float v1 = s_red[0][tile][lane][r0 + 1] + s_red[1][tile][lane][r0 + 1];
    *(float2*)(feats + (size_t)(n0 + n) * INTER + i0) = make_float2(v0, v1);
  }
}

// ---------------------------------------------------------------------------
// GEMM2: out[b][m] = b2[m] + sum_{s,i} (feats[b*20+s][i]+b1[i]) * W2[m][s*64+i]
// ---------------------------------------------------------------------------
__global__ __launch_bounds__(64) void gemm2_kernel(
    const float* __restrict__ feats,  // [NSEQ, 64]
    const float* __restrict__ b1,     // [64]
    const float* __restrict__ W2,     // [2, 1280]
    const float* __restrict__ b2,     // [2]
    float* __restrict__ out)          // [64, 2]
{
  const int b = blockIdx.x;
  const int i = threadIdx.x;
  const float bi = b1[i];
  float acc0 = 0.f, acc1 = 0.f;
  #pragma unroll
  for (int s = 0; s < SUB; ++s) {
    float f = feats[(size_t)(b * SUB + s) * INTER + i] + bi;
    acc0 = fmaf(f, W2[s * INTER + i], acc0);
    acc1 = fmaf(f, W2[1280 + s * INTER + i], acc1);
  }
  #pragma unroll
  for (int off = 32; off > 0; off >>= 1) {
    acc0 += __shfl_down(acc0, off);
    acc1 += __shfl_down(acc1, off);
  }
  if (i == 0) {
    out[b * 2 + 0] = acc0 + b2[0];
    out[b * 2 + 1] = acc1 + b2[1];
  }
}

// ---------------------------------------------------------------------------
extern "C" void kernel_launch(void* const* d_in, const int* in_sizes, int n_in,
                              void* d_out, int out_size, void* d_ws, size_t ws_size,
                              hipStream_t stream) {
  const float* x    = (const float*)d_in[0];
  // d_in[1] = metadata: unused by the reference
  const float* W_ih = (const float*)d_in[2];
  const float* W_hh = (const float*)d_in[3];
  const float* b_ih = (const float*)d_in[4];
  const float* b_hh = (const float*)d_in[5];
  const float* W1   = (const float*)d_in[6];
  const float* b1   = (const float*)d_in[7];
  const float* W2   = (const float*)d_in[8];
  const float* b2   = (const float*)d_in[9];
  float* out = (float*)d_out;

  // workspace: W1p packed split-bf16 [229376*16 ushort = 7.34 MB] + feats [327 KB]
  unsigned short* W1p = (unsigned short*)d_ws;
  float* feats = (float*)((char*)d_ws + (size_t)229376 * 16 * sizeof(unsigned short));

  prep_w1<<<896, 256, 0, stream>>>(W1, W1p);
  lstm_fused<<<NSEQ / NB, 512, 0, stream>>>(x, W_ih, W_hh, b_ih, b_hh, W1p, feats);
  gemm2_kernel<<<64, 64, 0, stream>>>(feats, b1, W2, b2, out);
}

// Round 8
// 401.134 us; speedup vs baseline: 9.4672x; 1.1594x over previous
//
#include <hip/hip_runtime.h>
#include <cstdint>

// Problem constants (from reference)
#define TSEQ 224
#define HID 128
#define NSEQ 1280           // BATCHES*SUB = 64*20
#define KTOT (TSEQ*HID)     // 28672
#define NB 16               // sequences per LSTM block
#define INTER 64
#define SUB 20

typedef short bf16x8 __attribute__((ext_vector_type(8)));
typedef float f32x4  __attribute__((ext_vector_type(4)));

__device__ __forceinline__ float fast_sigmoid(float a) {
  float e = __expf(-a);
  return __builtin_amdgcn_rcpf(1.0f + e);
}
__device__ __forceinline__ float fast_tanh(float a) {
  float e = __expf(-2.0f * a);
  return fmaf(2.0f, __builtin_amdgcn_rcpf(1.0f + e), -1.0f);
}

// Truncate-split packing: two fp32 -> one uint holding 2 bf16 (hi parts),
// and residual lo parts. Truncation keeps residual exactly representable.
__device__ __forceinline__ void split2(float a, float b,
                                       unsigned int& hi, unsigned int& lo) {
  unsigned int ua = __float_as_uint(a), ub = __float_as_uint(b);
  unsigned int ha = ua & 0xFFFF0000u,  hb = ub & 0xFFFF0000u;
  float ra = a - __uint_as_float(ha);
  float rb = b - __uint_as_float(hb);
  hi = (ha >> 16) | hb;
  lo = (__float_as_uint(ra) >> 16) | (__float_as_uint(rb) & 0xFFFF0000u);
}

// RNE round fp32 -> bf16 (4 VALU ops)
__device__ __forceinline__ unsigned short rne_bf16(float h) {
  unsigned int u = __float_as_uint(h);
  return (unsigned short)((u + 0x7FFFu + ((u >> 16) & 1u)) >> 16);
}

// ---------------------------------------------------------------------------
// prep_w1: repack W1 [64, KTOT] fp32 into split-bf16 per-lane fragment layout.
// chunk = t*16 + it*4 + kh*2 + kt2 ; within chunk: [lane(64)][hi8|lo8] ushort.
// ---------------------------------------------------------------------------
__global__ __launch_bounds__(256) void prep_w1(
    const float* __restrict__ W1, unsigned short* __restrict__ W1p)
{
  const int idx   = blockIdx.x * 256 + threadIdx.x;  // 229376 total
  const int lane  = idx & 63;
  const int chunk = idx >> 6;           // t*16 + it*4 + kh*2 + kt2
  const int kt2   = chunk & 1;
  const int kh    = (chunk >> 1) & 1;
  const int it    = (chunk >> 2) & 3;
  const int t     = chunk >> 4;
  const int row   = it * 16 + (lane & 15);
  const int col   = t * 128 + kh * 64 + kt2 * 32 + (lane >> 4) * 8;
  const float* src = W1 + (size_t)row * KTOT + col;
  union { bf16x8 v; unsigned int u[4]; } hi, lo;
  #pragma unroll
  for (int p = 0; p < 4; ++p) split2(src[2 * p], src[2 * p + 1], hi.u[p], lo.u[p]);
  unsigned short* dst = W1p + (size_t)chunk * 1024 + lane * 16;
  *(bf16x8*)dst       = hi.v;
  *(bf16x8*)(dst + 8) = lo.v;
}

// ---------------------------------------------------------------------------
// Fused MFMA LSTM + GEMM1, one barrier per step, 2-PASS split-bf16:
// h is stored as plain RNE bf16 (no lo residual); W (both W_hh and W1) stays
// split hi+lo. Per step this cuts MFMA 54->36, B-frag LDS reads 8->4
// ds_read_b128/wave, and deletes all v_perm unpacks — the three pipes whose
// SUM sets the barrier-coupled step time (R7: ~4300 cyc/step at pipe-sum
// ~2300). Error: |W·(h-bf16(h))| ~ 3e-4/step on gate preacts, contractive
// through forget-gate decay -> out err ~2e-4 vs 7.4e-4 threshold.
// ---------------------------------------------------------------------------
__attribute__((amdgpu_waves_per_eu(2, 2)))
__global__ __launch_bounds__(512) void lstm_fused(
    const float* __restrict__ x,      // [NSEQ, TSEQ]
    const float* __restrict__ W_ih,   // [512, 1]
    const float* __restrict__ W_hh,   // [512, 128]
    const float* __restrict__ b_ih,   // [512]
    const float* __restrict__ b_hh,   // [512]
    const unsigned short* __restrict__ W1p,  // packed split-bf16 W1
    float* __restrict__ feats)        // [NSEQ, 64]
{
  const int tid = threadIdx.x;
  const int w   = tid >> 6;          // wave 0..7
  const int l   = tid & 63;          // lane
  const int lm  = l & 15;            // seq col n (D/B); A-frag row
  const int lq  = l >> 4;            // quad
  const int n0  = blockIdx.x * NB;

  __shared__ float s_x[NB][228];                         // padded: bank spread
  __shared__ int   s_fz[NB];
  __shared__ int   s_len[NB];
  __shared__ int   s_maxlen;
  // h B-fragments (plain bf16), double-buffered:
  // s_hb[buf][kt][quad*16+n][j] = bf16(h[unit kt*32+quad*8+j][seq n])
  __shared__ __align__(16) unsigned short s_hb[2][4][64][8];   // 8 KB
  __shared__ __align__(16) float s_red[2][4][64][4];     // feats partials

  // ---- stage x (coalesced: 32 threads per sequence), find first zero
  if (tid < NB) s_fz[tid] = TSEQ;
  __syncthreads();
  {
    const int n = tid >> 5, j = tid & 31;
    const float* xrow = x + (size_t)(n0 + n) * TSEQ;
    #pragma unroll
    for (int i = 0; i < 7; ++i) {
      int t = j + 32 * i;
      float v = xrow[t];
      s_x[n][t] = v;
      if (v == 0.0f) atomicMin(&s_fz[n], t);
    }
  }
  // zero-init frag buffer 0 (h0 = 0): 4 KB
  ((uint2*)&s_hb[0][0][0][0])[tid] = make_uint2(0u, 0u);
  __syncthreads();
  if (tid < NB) {
    int fz = s_fz[tid];
    s_len[tid] = (fz == 0 || fz >= TSEQ) ? TSEQ : fz + 1;  // reference quirk
  }
  __syncthreads();
  if (tid == 0) {
    int m = 0;
    for (int n = 0; n < NB; ++n) m = max(m, s_len[n]);
    s_maxlen = m;
  }
  __syncthreads();
  const int maxlen = s_maxlen;
  const int len_lm = s_len[lm];      // len of the seq this lane updates/owns

  // ---- load LSTM A-fragments (W' permuted, split hi/lo) + per-lane consts
  bf16x8 whi[4][4], wlo[4][4];       // [mt][kt]
  #pragma unroll
  for (int mt = 0; mt < 4; ++mt) {
    const int MT   = w * 4 + mt;
    const int orow = (lm & 3) * 128 + MT * 4 + (lm >> 2);  // W' row permutation
    const float* wr = W_hh + (size_t)orow * HID;
    #pragma unroll
    for (int kt = 0; kt < 4; ++kt) {
      const int k0 = kt * 32 + lq * 8;
      union { bf16x8 v; unsigned int u[4]; } hi, lo;
      #pragma unroll
      for (int p = 0; p < 4; ++p)
        split2(wr[k0 + 2 * p], wr[k0 + 2 * p + 1], hi.u[p], lo.u[p]);
      whi[mt][kt] = hi.v;
      wlo[mt][kt] = lo.v;
    }
  }
  float bias_[4][4], wih_[4][4], c_[4];
  #pragma unroll
  for (int mt = 0; mt < 4; ++mt) {
    const int u_ = (w * 4 + mt) * 4 + lq;
    c_[mt] = 0.0f;
    #pragma unroll
    for (int r = 0; r < 4; ++r) {
      const int g = r * 128 + u_;       // r: 0=i 1=f 2=g~ 3=o
      bias_[mt][r] = b_ih[g] + b_hh[g];
      wih_[mt][r]  = W_ih[g];
    }
  }
  // ---- GEMM1 per-wave constants: wave w owns i-tile it = w>>1, kt-half kh
  const int it = w >> 1;
  const int kh = w & 1;
  const unsigned short* w1p_base = W1p + ((size_t)it * 4 + kh * 2) * 1024 + l * 16;
  f32x4 facc = {0.f, 0.f, 0.f, 0.f};

  for (int t = 0; t < maxlen; ++t) {
    const int p = t & 1;
    // W1 slice (t-1) fragments: 2 coalesced 32B loads (skip t=0: h_{-1}=0)
    bf16x8 w1hi[2], w1lo[2];
    if (t > 0) {
      const unsigned short* p0 = w1p_base + (size_t)(t - 1) * 16384;
      w1hi[0] = *(const bf16x8*)p0;
      w1lo[0] = *(const bf16x8*)(p0 + 8);
      w1hi[1] = *(const bf16x8*)(p0 + 1024);
      w1lo[1] = *(const bf16x8*)(p0 + 1024 + 8);
    }
    const float xv = s_x[lm][t];
    f32x4 acc[4];
    #pragma unroll
    for (int mt = 0; mt < 4; ++mt)
      #pragma unroll
      for (int r = 0; r < 4; ++r)
        acc[mt][r] = fmaf(wih_[mt][r], xv, bias_[mt][r]);
    // kt-outer: one b128 read per kt, 2-pass MFMA; GEMM1 folded in
    #pragma unroll
    for (int kt = 0; kt < 4; ++kt) {
      bf16x8 bh = *(const bf16x8*)&s_hb[p][kt][l][0];
      #pragma unroll
      for (int mt = 0; mt < 4; ++mt) {
        acc[mt] = __builtin_amdgcn_mfma_f32_16x16x32_bf16(whi[mt][kt], bh, acc[mt], 0, 0, 0);
        acc[mt] = __builtin_amdgcn_mfma_f32_16x16x32_bf16(wlo[mt][kt], bh, acc[mt], 0, 0, 0);
      }
      if (t > 0 && (kt >> 1) == kh) {
        const int kt2 = kt & 1;
        facc = __builtin_amdgcn_mfma_f32_16x16x32_bf16(w1hi[kt2], bh, facc, 0, 0, 0);
        facc = __builtin_amdgcn_mfma_f32_16x16x32_bf16(w1lo[kt2], bh, facc, 0, 0, 0);
      }
    }
    // in-lane LSTM update + direct bf16 frag write to buffer p^1
    #pragma unroll
    for (int mt = 0; mt < 4; ++mt) {
      float i_ = fast_sigmoid(acc[mt][0]);
      float f_ = fast_sigmoid(acc[mt][1]);
      float g_ = fast_tanh(acc[mt][2]);
      float o_ = fast_sigmoid(acc[mt][3]);
      c_[mt] = fmaf(f_, c_[mt], i_ * g_);
      float h_ = o_ * fast_tanh(c_[mt]);
      h_ = (t < len_lm) ? h_ : 0.0f;      // mask: matches reference hs zeroing
      const int u_ = 16 * w + 4 * mt + lq;  // unit this lane owns
      s_hb[p ^ 1][u_ >> 5][((u_ >> 3) & 3) * 16 + lm][u_ & 7] = rne_bf16(h_);
    }
    __syncthreads();
  }

  // ---- epilogue: GEMM1 for the final slice (maxlen-1) with h_{maxlen-1}
  {
    const int pe = maxlen & 1;
    const unsigned short* p0 = w1p_base + (size_t)(maxlen - 1) * 16384;
    bf16x8 w1hi[2], w1lo[2];
    w1hi[0] = *(const bf16x8*)p0;
    w1lo[0] = *(const bf16x8*)(p0 + 8);
    w1hi[1] = *(const bf16x8*)(p0 + 1024);
    w1lo[1] = *(const bf16x8*)(p0 + 1024 + 8);
    #pragma unroll
    for (int kt2 = 0; kt2 < 2; ++kt2) {
      const int kt = 2 * kh + kt2;
      bf16x8 bh = *(const bf16x8*)&s_hb[pe][kt][l][0];
      facc = __builtin_amdgcn_mfma_f32_16x16x32_bf16(w1hi[kt2], bh, facc, 0, 0, 0);
      facc = __builtin_amdgcn_mfma_f32_16x16x32_bf16(w1lo[kt2], bh, facc, 0, 0, 0);
    }
  }

  // ---- reduce kt-halves across wave pairs, write feats[n][i]
  *(f32x4*)&s_red[kh][it][l][0] = facc;
  __syncthreads();
  {
    const int n     = tid >> 5;          // 0..15
    const int ipair = tid & 31;          // 0..31
    const int i0    = ipair * 2;
    const int tile  = i0 >> 4;
    const int lqi   = (i0 & 15) >> 2;
    const int r0    = i0 & 3;            // 0 or 2
    const int lane  = lqi * 16 + n;
    float v0 = s_red[0][tile][lane][r0]     + s_red[1][tile][lane][r0];
    float v1 = s_red[0][tile][lane][r0 + 1] + s_red[1][tile][lane][r0 + 1];
    *(float2*)(feats + (size_t)(n0 + n) * INTER + i0) = make_float2(v0, v1);
  }
}

// ---------------------------------------------------------------------------
// GEMM2: out[b][m] = b2[m] + sum_{s,i} (feats[b*20+s][i]+b1[i]) * W2[m][s*64+i]
// ---------------------------------------------------------------------------
__global__ __launch_bounds__(64) void gemm2_kernel(
    const float* __restrict__ feats,  // [NSEQ, 64]
    const float* __restrict__ b1,     // [64]
    const float* __restrict__ W2,     // [2, 1280]
    const float* __restrict__ b2,     // [2]
    float* __restrict__ out)          // [64, 2]
{
  const int b = blockIdx.x;
  const int i = threadIdx.x;
  const float bi = b1[i];
  float acc0 = 0.f, acc1 = 0.f;
  #pragma unroll
  for (int s = 0; s < SUB; ++s) {
    float f = feats[(size_t)(b * SUB + s) * INTER + i] + bi;
    acc0 = fmaf(f, W2[s * INTER + i], acc0);
    acc1 = fmaf(f, W2[1280 + s * INTER + i], acc1);
  }
  #pragma unroll
  for (int off = 32; off > 0; off >>= 1) {
    acc0 += __shfl_down(acc0, off);
    acc1 += __shfl_down(acc1, off);
  }
  if (i == 0) {
    out[b * 2 + 0] = acc0 + b2[0];
    out[b * 2 + 1] = acc1 + b2[1];
  }
}

// ---------------------------------------------------------------------------
extern "C" void kernel_launch(void* const* d_in, const int* in_sizes, int n_in,
                              void* d_out, int out_size, void* d_ws, size_t ws_size,
                              hipStream_t stream) {
  const float* x    = (const float*)d_in[0];
  // d_in[1] = metadata: unused by the reference
  const float* W_ih = (const float*)d_in[2];
  const float* W_hh = (const float*)d_in[3];
  const float* b_ih = (const float*)d_in[4];
  const float* b_hh = (const float*)d_in[5];
  const float* W1   = (const float*)d_in[6];
  const float* b1   = (const float*)d_in[7];
  const float* W2   = (const float*)d_in[8];
  const float* b2   = (const float*)d_in[9];
  float* out = (float*)d_out;

  // workspace: W1p packed split-bf16 [229376*16 ushort = 7.34 MB] + feats [327 KB]
  unsigned short* W1p = (unsigned short*)d_ws;
  float* feats = (float*)((char*)d_ws + (size_t)229376 * 16 * sizeof(unsigned short));

  prep_w1<<<896, 256, 0, stream>>>(W1, W1p);
  lstm_fused<<<NSEQ / NB, 512, 0, stream>>>(x, W_ih, W_hh, b_ih, b_hh, W1p, feats);
  gemm2_kernel<<<64, 64, 0, stream>>>(feats, b1, W2, b2, out);
}